// Round 1
// baseline (1285.306 us; speedup 1.0000x reference)
//
#include <hip/hip_runtime.h>

// ---------------------------------------------------------------------------
// NodeNetwork: agg(sum over deg=16) -> concat(3x128) -> MLP(384-256-256-128)
//              -> row L2 normalize.  N=500000 rows.
// Strategy: memory-bound (4.1GB message stream). Fused single main kernel,
// bf16 MFMA (16x16x32) for the MLP, weights pre-packed to fragment order.
// ---------------------------------------------------------------------------

typedef short short8   __attribute__((ext_vector_type(8)));
typedef short short4_t __attribute__((ext_vector_type(4)));
typedef float f32x4    __attribute__((ext_vector_type(4)));

#define SWZ(row, off) ((off) ^ (((row) & 7) << 4))

__device__ __forceinline__ unsigned short f2bf(float f) {
    unsigned int u = __float_as_uint(f);
    u += 0x7fffu + ((u >> 16) & 1u);   // round-to-nearest-even
    return (unsigned short)(u >> 16);
}

// ---------------------------------------------------------------------------
// Weight prep: cast fp32->bf16 and pack into per-lane MFMA B-fragment order:
//   pw[((tn*KS + ks)*64 + lane)*8 + j] = bf16( W[k][n] )
//   with n = tn*16 + (lane&15), k = ks*32 + (lane>>4)*8 + j
// so a wave's B-fragment load is one fully-coalesced 1KB global_load_dwordx4.
// W1: [384][256] -> 16 tn x 12 ks ; W2: [256][256] -> 16 x 8 ; W3: [256][128] -> 8 x 8
// ---------------------------------------------------------------------------
__global__ void prep_weights(const float* __restrict__ W1,
                             const float* __restrict__ W2,
                             const float* __restrict__ W3,
                             short* __restrict__ pw1,
                             short* __restrict__ pw2,
                             short* __restrict__ pw3) {
    int idx = blockIdx.x * 256 + threadIdx.x;
    if (idx < 98304) {                       // W1
        int j = idx & 7, l = (idx >> 3) & 63, g = idx >> 9;
        int ks = g % 12, tn = g / 12;
        int n = tn * 16 + (l & 15);
        int k = ks * 32 + ((l >> 4) << 3) + j;
        pw1[idx] = (short)f2bf(W1[k * 256 + n]);
    } else if (idx < 98304 + 65536) {        // W2
        int e = idx - 98304;
        int j = e & 7, l = (e >> 3) & 63, g = e >> 9;
        int ks = g & 7, tn = g >> 3;
        int n = tn * 16 + (l & 15);
        int k = ks * 32 + ((l >> 4) << 3) + j;
        pw2[e] = (short)f2bf(W2[k * 256 + n]);
    } else if (idx < 98304 + 65536 + 32768) { // W3
        int e = idx - 98304 - 65536;
        int j = e & 7, l = (e >> 3) & 63, g = e >> 9;
        int ks = g & 7, tn = g >> 3;
        int n = tn * 16 + (l & 15);
        int k = ks * 32 + ((l >> 4) << 3) + j;
        pw3[e] = (short)f2bf(W3[k * 128 + n]);
    }
}

// ---------------------------------------------------------------------------
// Main fused kernel. 32 rows/block, 256 threads (4 waves).
// LDS (32KB total -> 4-5 blocks/CU):
//   regA [16KB]: h1 bf16 [32][256] (swz)   -> later out f32 [32][128] (swz)
//   regB [16KB]: bufP bf16 [32][128] (swz, lower 8KB) -> later h2 bf16 [32][256]
// All LDS tiles XOR-swizzled with ((row&7)<<4): row strides 256/512B are
// 0 mod 128B, which would otherwise serialize ds_read_b128 across banks.
// ---------------------------------------------------------------------------
__global__ __launch_bounds__(256, 4) void node_net(
    const float* __restrict__ msg,
    const float* __restrict__ feat,
    const float* __restrict__ glob,
    const float* __restrict__ b1v,
    const float* __restrict__ b2v,
    const float* __restrict__ b3v,
    const short* __restrict__ pw1,
    const short* __restrict__ pw2,
    const short* __restrict__ pw3,
    float* __restrict__ out,
    int n_rows)
{
    __shared__ char lds[32768];
    char* regA = lds;            // 16KB
    char* regB = lds + 16384;    // 16KB

    const int tid  = threadIdx.x;
    const int lane = tid & 63;
    const int w    = tid >> 6;
    const int lr   = lane & 15;  // row/col within 16x16 fragment
    const int lk   = lane >> 4;  // k-group (8 contiguous bf16 each)
    const long long r0 = (long long)blockIdx.x * 32;

    const f32x4 zero4 = {0.f, 0.f, 0.f, 0.f};

    f32x4 acc1[2][4];
    #pragma unroll
    for (int ri = 0; ri < 2; ++ri)
        #pragma unroll
        for (int ci = 0; ci < 4; ++ci) acc1[ri][ci] = zero4;

    // ================= GEMM1: x(=[agg|feat|glob]) @ W1, K split in 3 =======
    #pragma unroll
    for (int p = 0; p < 3; ++p) {
        // ---- fill bufP [32][128] bf16 with this K-part of x ----
        if (p == 0) {
            // message aggregation: 2 interleaved row-chains for load depth
            #pragma unroll
            for (int pass = 0; pass < 2; ++pass) {
                const int f4 = tid & 31;
                const int rA = (tid >> 5) + pass * 16;
                const int rB = rA + 8;
                const long long rowA = r0 + rA, rowB = r0 + rB;
                f32x4 a = zero4, b = zero4;
                const f32x4* mpA = (const f32x4*)msg + rowA * 512 + f4;
                const f32x4* mpB = (const f32x4*)msg + rowB * 512 + f4;
                if (rowB < n_rows) {         // common: both rows valid
                    #pragma unroll
                    for (int d = 0; d < 16; ++d) { a += mpA[d * 32]; b += mpB[d * 32]; }
                } else if (rowA < n_rows) {
                    #pragma unroll
                    for (int d = 0; d < 16; ++d) { a += mpA[d * 32]; }
                }
                short4_t sa, sb;
                sa[0] = (short)f2bf(a[0]); sa[1] = (short)f2bf(a[1]);
                sa[2] = (short)f2bf(a[2]); sa[3] = (short)f2bf(a[3]);
                sb[0] = (short)f2bf(b[0]); sb[1] = (short)f2bf(b[1]);
                sb[2] = (short)f2bf(b[2]); sb[3] = (short)f2bf(b[3]);
                *(short4_t*)(regB + SWZ(rA, rA * 256 + f4 * 8)) = sa;
                *(short4_t*)(regB + SWZ(rB, rB * 256 + f4 * 8)) = sb;
            }
        } else {
            const f32x4* sp = (const f32x4*)(p == 1 ? feat : glob);
            #pragma unroll
            for (int pass = 0; pass < 4; ++pass) {
                const int f4 = tid & 31;
                const int r  = (tid >> 5) + pass * 8;
                const long long row = r0 + r;
                f32x4 a = zero4;
                if (row < n_rows) a = sp[row * 32 + f4];
                short4_t s4;
                s4[0] = (short)f2bf(a[0]); s4[1] = (short)f2bf(a[1]);
                s4[2] = (short)f2bf(a[2]); s4[3] = (short)f2bf(a[3]);
                *(short4_t*)(regB + SWZ(r, r * 256 + f4 * 8)) = s4;
            }
        }
        __syncthreads();

        // ---- 4 K-steps of MFMA on this part ----
        #pragma unroll
        for (int s = 0; s < 4; ++s) {
            const int ks = p * 4 + s;
            short8 a[2], b[4];
            #pragma unroll
            for (int ri = 0; ri < 2; ++ri) {
                int row = ri * 16 + lr;
                int off = row * 256 + s * 64 + lk * 16;
                a[ri] = *(const short8*)(regB + SWZ(row, off));
            }
            #pragma unroll
            for (int ci = 0; ci < 4; ++ci) {
                int tn = w * 4 + ci;
                b[ci] = *(const short8*)(pw1 + (((tn * 12 + ks) * 64 + lane) << 3));
            }
            #pragma unroll
            for (int ri = 0; ri < 2; ++ri)
                #pragma unroll
                for (int ci = 0; ci < 4; ++ci)
                    acc1[ri][ci] = __builtin_amdgcn_mfma_f32_16x16x32_bf16(
                        a[ri], b[ci], acc1[ri][ci], 0, 0, 0);
        }
        __syncthreads();
    }

    // ---- epilogue 1: +b1, ReLU, bf16 -> h1 in regA ----
    #pragma unroll
    for (int ci = 0; ci < 4; ++ci) {
        int col = w * 64 + ci * 16 + lr;
        float bias = b1v[col];
        #pragma unroll
        for (int ri = 0; ri < 2; ++ri)
            #pragma unroll
            for (int i = 0; i < 4; ++i) {
                int row = ri * 16 + lk * 4 + i;
                float v = fmaxf(acc1[ri][ci][i] + bias, 0.f);
                int off = row * 512 + col * 2;
                *(short*)(regA + SWZ(row, off)) = (short)f2bf(v);
            }
    }
    __syncthreads();

    // ================= GEMM2: h1 @ W2 ======================================
    f32x4 acc2[2][4];
    #pragma unroll
    for (int ri = 0; ri < 2; ++ri)
        #pragma unroll
        for (int ci = 0; ci < 4; ++ci) acc2[ri][ci] = zero4;

    #pragma unroll
    for (int s = 0; s < 8; ++s) {
        short8 a[2], b[4];
        #pragma unroll
        for (int ri = 0; ri < 2; ++ri) {
            int row = ri * 16 + lr;
            int off = row * 512 + s * 64 + lk * 16;
            a[ri] = *(const short8*)(regA + SWZ(row, off));
        }
        #pragma unroll
        for (int ci = 0; ci < 4; ++ci) {
            int tn = w * 4 + ci;
            b[ci] = *(const short8*)(pw2 + (((tn * 8 + s) * 64 + lane) << 3));
        }
        #pragma unroll
        for (int ri = 0; ri < 2; ++ri)
            #pragma unroll
            for (int ci = 0; ci < 4; ++ci)
                acc2[ri][ci] = __builtin_amdgcn_mfma_f32_16x16x32_bf16(
                    a[ri], b[ci], acc2[ri][ci], 0, 0, 0);
    }

    // ---- epilogue 2: +b2, ReLU, bf16 -> h2 in regB (bufP is dead) ----
    #pragma unroll
    for (int ci = 0; ci < 4; ++ci) {
        int col = w * 64 + ci * 16 + lr;
        float bias = b2v[col];
        #pragma unroll
        for (int ri = 0; ri < 2; ++ri)
            #pragma unroll
            for (int i = 0; i < 4; ++i) {
                int row = ri * 16 + lk * 4 + i;
                float v = fmaxf(acc2[ri][ci][i] + bias, 0.f);
                int off = row * 512 + col * 2;
                *(short*)(regB + SWZ(row, off)) = (short)f2bf(v);
            }
    }
    __syncthreads();

    // ================= GEMM3: h2 @ W3 ======================================
    f32x4 acc3[2][2];
    #pragma unroll
    for (int ri = 0; ri < 2; ++ri)
        #pragma unroll
        for (int ci = 0; ci < 2; ++ci) acc3[ri][ci] = zero4;

    #pragma unroll
    for (int s = 0; s < 8; ++s) {
        short8 a[2], b[2];
        #pragma unroll
        for (int ri = 0; ri < 2; ++ri) {
            int row = ri * 16 + lr;
            int off = row * 512 + s * 64 + lk * 16;
            a[ri] = *(const short8*)(regB + SWZ(row, off));
        }
        #pragma unroll
        for (int ci = 0; ci < 2; ++ci) {
            int tn = w * 2 + ci;
            b[ci] = *(const short8*)(pw3 + (((tn * 8 + s) * 64 + lane) << 3));
        }
        #pragma unroll
        for (int ri = 0; ri < 2; ++ri)
            #pragma unroll
            for (int ci = 0; ci < 2; ++ci)
                acc3[ri][ci] = __builtin_amdgcn_mfma_f32_16x16x32_bf16(
                    a[ri], b[ci], acc3[ri][ci], 0, 0, 0);
    }

    // ---- epilogue 3: +b3, f32 -> out tile in regA (h1 is dead) ----
    #pragma unroll
    for (int ci = 0; ci < 2; ++ci) {
        int col = w * 32 + ci * 16 + lr;
        float bias = b3v[col];
        #pragma unroll
        for (int ri = 0; ri < 2; ++ri)
            #pragma unroll
            for (int i = 0; i < 4; ++i) {
                int row = ri * 16 + lk * 4 + i;
                float v = acc3[ri][ci][i] + bias;
                int off = row * 512 + col * 4;
                *(float*)(regA + SWZ(row, off)) = v;
            }
    }
    __syncthreads();

    // ---- row-wise L2 normalize + coalesced store ----
    #pragma unroll
    for (int pass = 0; pass < 4; ++pass) {
        const int r  = (tid >> 5) + pass * 8;   // 32 lanes per row
        const int fl = tid & 31;
        int off = r * 512 + fl * 16;
        f32x4 v = *(const f32x4*)(regA + SWZ(r, off));
        float ss = v[0]*v[0] + v[1]*v[1] + v[2]*v[2] + v[3]*v[3];
        ss += __shfl_xor(ss, 1, 32);
        ss += __shfl_xor(ss, 2, 32);
        ss += __shfl_xor(ss, 4, 32);
        ss += __shfl_xor(ss, 8, 32);
        ss += __shfl_xor(ss, 16, 32);
        float inv = 1.f / (sqrtf(ss) + 1e-8f);
        long long row = r0 + r;
        if (row < n_rows) {
            f32x4 o = v * inv;
            ((f32x4*)out)[row * 32 + fl] = o;
        }
    }
}

// ---------------------------------------------------------------------------
extern "C" void kernel_launch(void* const* d_in, const int* in_sizes, int n_in,
                              void* d_out, int out_size, void* d_ws, size_t ws_size,
                              hipStream_t stream) {
    const float* msg  = (const float*)d_in[0];
    const float* feat = (const float*)d_in[1];
    const float* glob = (const float*)d_in[2];
    const float* W1   = (const float*)d_in[3];
    const float* b1   = (const float*)d_in[4];
    const float* W2   = (const float*)d_in[5];
    const float* b2   = (const float*)d_in[6];
    const float* W3   = (const float*)d_in[7];
    const float* b3   = (const float*)d_in[8];
    float* out = (float*)d_out;

    const int n_rows = in_sizes[1] / 128;   // features is [N,128]

    short* pw1 = (short*)d_ws;              // 98304 bf16
    short* pw2 = pw1 + 98304;               // 65536 bf16
    short* pw3 = pw2 + 65536;               // 32768 bf16

    hipLaunchKernelGGL(prep_weights, dim3(768), dim3(256), 0, stream,
                       W1, W2, W3, pw1, pw2, pw3);

    const int nblocks = (n_rows + 31) / 32;
    hipLaunchKernelGGL(node_net, dim3(nblocks), dim3(256), 0, stream,
                       msg, feat, glob, b1, b2, b3, pw1, pw2, pw3, out, n_rows);
}